// Round 4
// baseline (97.285 us; speedup 1.0000x reference)
//
#include <hip/hip_runtime.h>

// CombinedLoss: 0.99 * dice + 0.01 * mean(phi * sigmoid(pred))
// phi = signed exact EDT of targets mask (16 x 512 x 512), |phi|>1e5 -> 0.
//
// Round 4: SINGLE dispatch. Each of 256 blocks owns a 32-row slab; computes
// 1D row-distance fields for slab+16-row halo into LDS as u8 pairs
// (g0 = dist-to-bg, g1 = dist-to-fg, 255 = ">=255 / none" sentinel;
// 64 rows x 512 px x 2 B = 64 KB -> 2 blocks/CU), runs the column
// lower-envelope scan from LDS, accumulates the four loss sums, then a
// flag-based completion protocol lets block 0 do the final reduction in
// the same dispatch (all 256 blocks co-resident: capacity 2/CU x 256 CU).
// Any pixel not provably resolved (m2 > 17^2 after the halo scan, or any
// clamped/sentinel byte winning) takes an exact global-t fallback, so the
// kernel is exact for ANY input, not just Bernoulli(0.5) masks.
//
// ws: [0,8192) double partials[256][4]; [8192,9216) u32 flags[256].
// Both fully rewritten every call (flags poison 0xAAAAAAAA != MAGIC).

#define HH 512
#define WW 512
#define HALO 16
#define TR 64
#define NT 512
#define NBLK 256
#define MAGIC 0x600DF00Du

// exact per-pixel fallback: full-image search, fresh upper bound (rare path)
__device__ __noinline__ float fallback_exact(const int* __restrict__ t,
                                             int n, int y, int x, bool fg) {
    float m2 = 4.2e9f;
    const int* tn = t + (n << 18);
    for (int yy = 0; yy < HH; ++yy) {
        float dy = (float)(yy - y);
        float dy2 = dy * dy;
        if (dy2 >= m2) continue;
        const int* row = tn + (yy << 9);
        int lim = (int)sqrtf(m2 - dy2);
        if (lim > 511) lim = 511;
        for (int dx = 0; dx <= lim; ++dx) {
            bool hit = false;
            int xl = x - dx, xr = x + dx;
            if (xl >= 0) { int v = row[xl]; hit = fg ? (v == 0) : (v != 0); }
            if (!hit && xr < WW) { int v = row[xr]; hit = fg ? (v == 0) : (v != 0); }
            if (hit) {
                float c = fmaf((float)dx, (float)dx, dy2);
                if (c < m2) m2 = c;
                break;
            }
        }
    }
    return m2;
}

__global__ __launch_bounds__(NT, 4) void edt_fused_all(const int* __restrict__ t,
                                                       const float* __restrict__ pred,
                                                       double* __restrict__ partials,
                                                       unsigned int* __restrict__ flags,
                                                       float* __restrict__ out) {
    __shared__ unsigned int gl[TR][WW / 2];   // 64 KB; word = 2 px: [g0,g1,g0,g1] bytes
    __shared__ double sred[8][4];

    const int n     = blockIdx.x >> 4;
    const int y0    = (blockIdx.x & 15) << 5;
    const int rbase = y0 - HALO;
    const int wave  = threadIdx.x >> 6;   // 0..7
    const int lane  = threadIdx.x & 63;
    const int x0    = lane << 3;
    const float BIG = 3.0e37f;

    // ---------------- phase 1: 1D row scans (both fields) -> LDS u8 pairs ----------
    for (int rr = wave; rr < TR; rr += 8) {
        const int gy = rbase + rr;
        if (gy < 0 || gy >= HH) {
            uint4 s = {~0u, ~0u, ~0u, ~0u};           // g0=g1=255 everywhere
            *((uint4*)&gl[rr][x0 >> 1]) = s;
            continue;
        }
        const int4* tp = (const int4*)(t + (n << 18) + (gy << 9) + x0);
        int4 ta = tp[0], tb = tp[1];
        int tv[8] = {ta.x, ta.y, ta.z, ta.w, tb.x, tb.y, tb.z, tb.w};

        float pen[2][8];
#pragma unroll
        for (int i = 0; i < 8; ++i) {
            bool fg = (tv[i] != 0);
            pen[0][i] = fg ? 1.0e6f : 0.0f;   // sites = background
            pen[1][i] = fg ? 0.0f : 1.0e6f;   // sites = foreground
        }

        unsigned int gb[2][8];
#pragma unroll
        for (int f = 0; f < 2; ++f) {
            float pf[8];
            float run = BIG;
#pragma unroll
            for (int i = 0; i < 8; ++i) { run = fminf(run, pen[f][i] - (float)(x0 + i)); pf[i] = run; }
            float incl = run;
#pragma unroll
            for (int off = 1; off < 64; off <<= 1) {
                float u = __shfl_up(incl, (unsigned)off, 64);
                if (lane >= off) incl = fminf(incl, u);
            }
            float excl = __shfl_up(incl, 1u, 64);
            if (lane == 0) excl = BIG;

            float sf[8];
            run = BIG;
#pragma unroll
            for (int i = 7; i >= 0; --i) { run = fminf(run, pen[f][i] + (float)(x0 + i)); sf[i] = run; }
            float inclb = run;
#pragma unroll
            for (int off = 1; off < 64; off <<= 1) {
                float u = __shfl_down(inclb, (unsigned)off, 64);
                if (lane + off < 64) inclb = fminf(inclb, u);
            }
            float exclb = __shfl_down(inclb, 1u, 64);
            if (lane == 63) exclb = BIG;

#pragma unroll
            for (int i = 0; i < 8; ++i) {
                float xa = (float)(x0 + i);
                float fa = xa + fminf(pf[i], excl);
                float ba = -xa + fminf(sf[i], exclb);
                gb[f][i] = (unsigned int)fminf(fminf(fa, ba), 255.0f);
            }
        }

        unsigned int pk[4];
#pragma unroll
        for (int w = 0; w < 4; ++w)
            pk[w] = gb[0][2 * w] | (gb[1][2 * w] << 8) |
                    (gb[0][2 * w + 1] << 16) | (gb[1][2 * w + 1] << 24);
        uint4 o = {pk[0], pk[1], pk[2], pk[3]};
        *((uint4*)&gl[rr][x0 >> 1]) = o;
    }
    __syncthreads();

    // ---------------- phase 2: column scan + fused loss sums ----------------
    double s_b = 0.0, s_p = 0.0, s_i = 0.0;
    int s_t = 0;

#pragma unroll 1
    for (int grp = 0; grp < 8; ++grp) {
        const int pid = (grp * NT + threadIdx.x) << 2;   // 4 consecutive px
        const int yl  = pid >> 9;                        // 0..31
        const int x   = pid & 511;
        const int r   = yl + HALO;                       // 16..47

        const float4 p4 = *((const float4*)(pred + (n << 18) + ((y0 + yl) << 9) + x));
        const float pv[4] = {p4.x, p4.y, p4.z, p4.w};

        const uint2 ow = *((const uint2*)&gl[r][x >> 1]);
        const unsigned int w01[2] = {ow.x, ow.y};

        bool fg[4];
        int  shl[4];
        float m2[4];
        float mx = 0.0f;
#pragma unroll
        for (int j = 0; j < 4; ++j) {
            unsigned int word = w01[j >> 1];
            int sh16 = (j & 1) << 4;
            unsigned int g0 = (word >> sh16) & 0xFFu;
            unsigned int g1 = (word >> (sh16 + 8)) & 0xFFu;
            fg[j]  = (g1 == 0u);              // exactly one of g0/g1 is 0
            shl[j] = sh16 + (fg[j] ? 0 : 8);
            float gv = (float)(g0 | g1);
            m2[j] = gv * gv;
            mx = fmaxf(mx, m2[j]);
        }

#pragma unroll 1
        for (int k = 1; k <= HALO; ++k) {
            float k2 = (float)(k * k);
            if (k2 >= mx) break;
            const uint2 d2v = *((const uint2*)&gl[r - k][x >> 1]);
            const uint2 u2v = *((const uint2*)&gl[r + k][x >> 1]);
            const unsigned int wd[2] = {d2v.x, d2v.y};
            const unsigned int wu[2] = {u2v.x, u2v.y};
            mx = 0.0f;
#pragma unroll
            for (int j = 0; j < 4; ++j) {
                if (k2 < m2[j]) {
                    float a = (float)((wd[j >> 1] >> shl[j]) & 0xFFu);
                    float b = (float)((wu[j >> 1] >> shl[j]) & 0xFFu);
                    m2[j] = fminf(m2[j], fminf(fmaf(a, a, k2), fmaf(b, b, k2)));
                }
                mx = fmaxf(mx, m2[j]);
            }
        }

        // resolved iff m2 <= 17^2: any k>HALO candidate >= 289, any clamped/
        // sentinel byte contributes >= 255^2 > 289. Otherwise exact fallback.
        if (mx > 289.0f) {
#pragma unroll
            for (int j = 0; j < 4; ++j)
                if (m2[j] > 289.0f)
                    m2[j] = fallback_exact(t, n, y0 + yl, x + j, fg[j]);
        }

#pragma unroll
        for (int j = 0; j < 4; ++j) {
            float p = 1.0f / (1.0f + expf(-pv[j]));
            float d = sqrtf(m2[j]);
            float phi = fg[j] ? -d : d;
            if (d > 1.0e4f) phi = 0.0f;   // "no site" only; real d <= 722
            s_b += (double)(phi * p);
            s_p += (double)p;
            if (fg[j]) { s_i += (double)p; s_t += 1; }
        }
    }
    double s_tt = (double)s_t;

    // ---------------- block reduce -> partials[b], release flag ----------------
#pragma unroll
    for (int off = 32; off > 0; off >>= 1) {
        s_b  += __shfl_xor(s_b,  off, 64);
        s_p  += __shfl_xor(s_p,  off, 64);
        s_i  += __shfl_xor(s_i,  off, 64);
        s_tt += __shfl_xor(s_tt, off, 64);
    }
    if (lane == 0) {
        sred[wave][0] = s_b; sred[wave][1] = s_p; sred[wave][2] = s_i; sred[wave][3] = s_tt;
    }
    __syncthreads();
    if (threadIdx.x == 0) {
        double* dst = partials + (size_t)blockIdx.x * 4;
#pragma unroll
        for (int c = 0; c < 4; ++c) {
            double acc = 0.0;
#pragma unroll
            for (int wv = 0; wv < 8; ++wv) acc += sred[wv][c];
            dst[c] = acc;
        }
        __threadfence();
        __hip_atomic_store(&flags[blockIdx.x], MAGIC, __ATOMIC_RELEASE,
                           __HIP_MEMORY_SCOPE_AGENT);
    }
    if (blockIdx.x != 0) return;

    // ---------------- block 0: final reduction (all blocks co-resident) --------
    double a0 = 0.0, a1 = 0.0, a2 = 0.0, a3 = 0.0;
    if (threadIdx.x < NBLK) {
        while (__hip_atomic_load(&flags[threadIdx.x], __ATOMIC_ACQUIRE,
                                 __HIP_MEMORY_SCOPE_AGENT) != MAGIC) { }
        const double* src = partials + (size_t)threadIdx.x * 4;
        a0 = src[0]; a1 = src[1]; a2 = src[2]; a3 = src[3];
    }
#pragma unroll
    for (int off = 32; off > 0; off >>= 1) {
        a0 += __shfl_xor(a0, off, 64);
        a1 += __shfl_xor(a1, off, 64);
        a2 += __shfl_xor(a2, off, 64);
        a3 += __shfl_xor(a3, off, 64);
    }
    __syncthreads();   // retire previous use of sred
    if (lane == 0) { sred[wave][0] = a0; sred[wave][1] = a1; sred[wave][2] = a2; sred[wave][3] = a3; }
    __syncthreads();
    if (threadIdx.x == 0) {
        double sb = 0.0, sp = 0.0, si = 0.0, st = 0.0;
#pragma unroll
        for (int wv = 0; wv < 8; ++wv) {   // waves 4..7 contributed zeros
            sb += sred[wv][0]; sp += sred[wv][1]; si += sred[wv][2]; st += sred[wv][3];
        }
        double dice = 1.0 - (2.0 * si + 1e-6) / (sp + st + 1e-6);
        double boundary = sb / (double)(16 * 512 * 512);
        out[0] = (float)(0.99 * dice + 0.01 * boundary);
    }
}

extern "C" void kernel_launch(void* const* d_in, const int* in_sizes, int n_in,
                              void* d_out, int out_size, void* d_ws, size_t ws_size,
                              hipStream_t stream) {
    const float* pred = (const float*)d_in[0];
    const int*   targ = (const int*)d_in[1];
    double* partials = (double*)d_ws;                         // 8192 B
    unsigned int* flags = (unsigned int*)((char*)d_ws + 8192); // 1024 B
    float* out = (float*)d_out;

    edt_fused_all<<<NBLK, NT, 0, stream>>>(targ, pred, partials, flags, out);
}